// Round 1
// baseline (967.838 us; speedup 1.0000x reference)
//
#include <hip/hip_runtime.h>

// Problem: B=4, C=512, H=W=64 -> N=4096 tokens, KEY_DIM=VALUE_DIM=512.
// Pipeline:
//   K1 (qkv_proj): Qt,Kt (B,N,D) bf16 token-major; Vd (B,D,N) bf16 d-major. All in d_ws.
//   K2 (attn):     per-WG 64 queries; sweep1: l_j = sum_i exp(q.k/sqrt(D)) (no max-sub
//                  needed: logits ~ N(0,1)); sweep2: P=exp*1/l, O=V.P^T, colsum via LDS.
// All matmul work on v_mfma_f32_16x16x32_bf16 (fp32 accum).

typedef short bf16x8 __attribute__((ext_vector_type(8)));
typedef float f32x4 __attribute__((ext_vector_type(4)));

#define NTOK 4096
#define DDIM 512
#define NB   4

__device__ __forceinline__ unsigned short f32_bf16(float f) {
  union { float f; unsigned u; } v; v.f = f;
  unsigned r = v.u + 0x7FFFu + ((v.u >> 16) & 1u);  // RNE
  return (unsigned short)(r >> 16);
}

// ---------------------------------------------------------------------------
// K1: QKV projection.  Q[n,d] = sum_c x[c,n] * Wq[d,c]  (x is (C,N) per batch)
// WG tile: 64 tokens x 64 d.  Q/K computed as D[m=token][n=d], V as D[m=d][n=token]
// so every epilogue store is along the fast axis of its destination.
// ---------------------------------------------------------------------------
__global__ __launch_bounds__(256, 4) void qkv_proj(
    const float* __restrict__ x,
    const float* __restrict__ Wq,
    const float* __restrict__ Wk,
    const float* __restrict__ Wv,
    unsigned short* __restrict__ Qt,
    unsigned short* __restrict__ Kt,
    unsigned short* __restrict__ Vd)
{
  const int nt0 = blockIdx.x * 64;   // token tile
  const int d0  = blockIdx.y * 64;   // feature tile
  const int b   = blockIdx.z;
  const int tid = threadIdx.x;
  const int wave = tid >> 6;
  const int lane = tid & 63;
  const int l15  = lane & 15;
  const int quad = lane >> 4;

  // rows padded to 40 bf16 (80 B): 16B-aligned b128 rows, 2-way-max read conflicts
  __shared__ __align__(16) unsigned short Xt[64 * 40];     // [token][c]
  __shared__ __align__(16) unsigned short Wl[3][64 * 40];  // [q/k/v][d][c]

  f32x4 aq[4], ak[4], av[4];
#pragma unroll
  for (int i = 0; i < 4; ++i) {
    aq[i] = (f32x4){0.f,0.f,0.f,0.f};
    ak[i] = (f32x4){0.f,0.f,0.f,0.f};
    av[i] = (f32x4){0.f,0.f,0.f,0.f};
  }

  const float* xb = x + (size_t)b * DDIM * NTOK + nt0;
  const int xn  = tid & 63;   // token for X staging
  const int xc8 = tid >> 6;   // c-group (8 c each)
  const int wc8 = tid & 3;    // c-group for W staging
  const int wdd = tid >> 2;   // d row for W staging

  for (int cc = 0; cc < DDIM; cc += 32) {
    __syncthreads();
    {  // X: transpose-stage. global reads coalesced across lanes (consecutive n).
      bf16x8 t;
#pragma unroll
      for (int j = 0; j < 8; ++j)
        t[j] = (short)f32_bf16(xb[(size_t)(cc + xc8 * 8 + j) * NTOK + xn]);
      *(bf16x8*)(&Xt[xn * 40 + xc8 * 8]) = t;
    }
    {  // W: already c-fastest in global.
      const float* wsrc[3] = {Wq, Wk, Wv};
#pragma unroll
      for (int m = 0; m < 3; ++m) {
        const float* src = wsrc[m] + (size_t)(d0 + wdd) * DDIM + cc + wc8 * 8;
        bf16x8 t;
#pragma unroll
        for (int j = 0; j < 8; ++j) t[j] = (short)f32_bf16(src[j]);
        *(bf16x8*)(&Wl[m][wdd * 40 + wc8 * 8]) = t;
      }
    }
    __syncthreads();

    bf16x8 xa  = *(const bf16x8*)(&Xt[(wave * 16 + l15) * 40 + quad * 8]);     // A: m=token
    bf16x8 wva = *(const bf16x8*)(&Wl[2][(wave * 16 + l15) * 40 + quad * 8]);  // A: m=d
#pragma unroll
    for (int nt = 0; nt < 4; ++nt) {
      bf16x8 wqf = *(const bf16x8*)(&Wl[0][(nt * 16 + l15) * 40 + quad * 8]);  // B: n=d
      bf16x8 wkf = *(const bf16x8*)(&Wl[1][(nt * 16 + l15) * 40 + quad * 8]);
      bf16x8 xbf = *(const bf16x8*)(&Xt[(nt * 16 + l15) * 40 + quad * 8]);     // B: n=token
      aq[nt] = __builtin_amdgcn_mfma_f32_16x16x32_bf16(xa,  wqf, aq[nt], 0, 0, 0);
      ak[nt] = __builtin_amdgcn_mfma_f32_16x16x32_bf16(xa,  wkf, ak[nt], 0, 0, 0);
      av[nt] = __builtin_amdgcn_mfma_f32_16x16x32_bf16(wva, xbf, av[nt], 0, 0, 0);
    }
  }

  // epilogue: C/D layout col=lane&15, row=quad*4+reg
#pragma unroll
  for (int nt = 0; nt < 4; ++nt) {
#pragma unroll
    for (int r = 0; r < 4; ++r) {
      const int tokq = nt0 + wave * 16 + quad * 4 + r;
      const int dq   = d0 + nt * 16 + l15;
      Qt[((size_t)b * NTOK + tokq) * DDIM + dq] = f32_bf16(aq[nt][r]);
      Kt[((size_t)b * NTOK + tokq) * DDIM + dq] = f32_bf16(ak[nt][r]);
      const int dv   = d0 + wave * 16 + quad * 4 + r;
      const int tokv = nt0 + nt * 16 + l15;
      Vd[((size_t)b * DDIM + dv) * NTOK + tokv] = f32_bf16(av[nt][r]);
    }
  }
}

// ---------------------------------------------------------------------------
// K2: fused attention. WG = (batch, 64-query block), 256 threads.
// ---------------------------------------------------------------------------
#define BQ   64
#define BK   64
#define DSUB 256
#define KROW 264   // 256 + 8 pad (row = 528 B, 16B aligned, 2-way-max conflicts)
#define PROW 72    // 64 + 8 pad

__global__ __launch_bounds__(256, 2) void attn_fused(
    const unsigned short* __restrict__ Qt,
    const unsigned short* __restrict__ Kt,
    const unsigned short* __restrict__ Vd,
    float* __restrict__ out,
    float* __restrict__ scores_out)
{
  const int q0  = blockIdx.x * BQ;
  const int b   = blockIdx.y;
  const int tid = threadIdx.x;
  const int wave = tid >> 6;
  const int lane = tid & 63;
  const int l15  = lane & 15;
  const int quad = lane >> 4;

  __shared__ __align__(16) unsigned short Klds[BK * KROW];  // 33792 B
  __shared__ __align__(16) unsigned short Plds[BQ * PROW];  //  9216 B
  __shared__ float csum[NTOK];                              // 16384 B

  for (int i = tid; i < NTOK; i += 256) csum[i] = 0.f;

  // Q fragments for this wave's 16 rows, all 512 d: 16 chunks x 4 VGPRs, loaded once.
  bf16x8 qf[16];
  {
    const unsigned short* qp =
        Qt + ((size_t)b * NTOK + q0 + wave * 16 + l15) * DDIM + quad * 8;
#pragma unroll
    for (int dc = 0; dc < 16; ++dc) qf[dc] = *(const bf16x8*)(qp + dc * 32);
  }

  const float sc = 0.044194173824159216f;  // 1/sqrt(512)
  const unsigned short* kb = Kt + (size_t)b * NTOK * DDIM;

  // ---------------- sweep 1: row sums l_j ----------------
  float lsum[4] = {0.f, 0.f, 0.f, 0.f};
  for (int kc = 0; kc < NTOK / BK; ++kc) {
    const unsigned short* ksrc = kb + (size_t)kc * BK * DDIM;
    f32x4 sacc[4];
#pragma unroll
    for (int i = 0; i < 4; ++i) sacc[i] = (f32x4){0.f,0.f,0.f,0.f};
#pragma unroll
    for (int dsi = 0; dsi < 2; ++dsi) {
      __syncthreads();
#pragma unroll
      for (int it = 0; it < 8; ++it) {
        const int li = tid + it * 256;
        const int ri = li >> 5;
        const int c8 = li & 31;
        *(bf16x8*)(&Klds[ri * KROW + c8 * 8]) =
            *(const bf16x8*)(ksrc + (size_t)ri * DDIM + dsi * DSUB + c8 * 8);
      }
      __syncthreads();
#pragma unroll
      for (int dc = 0; dc < 8; ++dc) {
        const int ko = dc * 32 + quad * 8;
        const bf16x8 a = qf[dsi * 8 + dc];
#pragma unroll
        for (int nt = 0; nt < 4; ++nt) {
          bf16x8 kf = *(const bf16x8*)(&Klds[(nt * 16 + l15) * KROW + ko]);
          sacc[nt] = __builtin_amdgcn_mfma_f32_16x16x32_bf16(a, kf, sacc[nt], 0, 0, 0);
        }
      }
    }
#pragma unroll
    for (int nt = 0; nt < 4; ++nt)
#pragma unroll
      for (int r = 0; r < 4; ++r) lsum[r] += __expf(sacc[nt][r] * sc);
  }
  float wrec[4];
#pragma unroll
  for (int r = 0; r < 4; ++r) {  // reduce over the 16 cols held by the quad's lanes
    float v = lsum[r];
    v += __shfl_xor(v, 1);
    v += __shfl_xor(v, 2);
    v += __shfl_xor(v, 4);
    v += __shfl_xor(v, 8);
    wrec[r] = 1.0f / v;
  }

  // ---------------- sweep 2: O = V.P^T, colsum ----------------
  f32x4 o[8][4];
#pragma unroll
  for (int i = 0; i < 8; ++i)
#pragma unroll
    for (int j = 0; j < 4; ++j) o[i][j] = (f32x4){0.f,0.f,0.f,0.f};

  // this wave owns d in [wave*128, wave*128+128)
  const unsigned short* vb =
      Vd + ((size_t)b * DDIM + wave * 128 + l15) * NTOK + quad * 8;

  for (int kc = 0; kc < NTOK / BK; ++kc) {
    const int i0 = kc * BK;
    const unsigned short* ksrc = kb + (size_t)i0 * DDIM;
    f32x4 sacc[4];
#pragma unroll
    for (int i = 0; i < 4; ++i) sacc[i] = (f32x4){0.f,0.f,0.f,0.f};
#pragma unroll
    for (int dsi = 0; dsi < 2; ++dsi) {
      __syncthreads();  // also guarantees prior PV reads of Plds are done
#pragma unroll
      for (int it = 0; it < 8; ++it) {
        const int li = tid + it * 256;
        const int ri = li >> 5;
        const int c8 = li & 31;
        *(bf16x8*)(&Klds[ri * KROW + c8 * 8]) =
            *(const bf16x8*)(ksrc + (size_t)ri * DDIM + dsi * DSUB + c8 * 8);
      }
      __syncthreads();
#pragma unroll
      for (int dc = 0; dc < 8; ++dc) {
        const int ko = dc * 32 + quad * 8;
        const bf16x8 a = qf[dsi * 8 + dc];
#pragma unroll
        for (int nt = 0; nt < 4; ++nt) {
          bf16x8 kf = *(const bf16x8*)(&Klds[(nt * 16 + l15) * KROW + ko]);
          sacc[nt] = __builtin_amdgcn_mfma_f32_16x16x32_bf16(a, kf, sacc[nt], 0, 0, 0);
        }
      }
    }

    // P = exp(s)/l (fp32), column partial sums, stage P to LDS as bf16
    float pv[4][4];
#pragma unroll
    for (int nt = 0; nt < 4; ++nt) {
      float cs = 0.f;
#pragma unroll
      for (int r = 0; r < 4; ++r) {
        const float p = __expf(sacc[nt][r] * sc) * wrec[r];
        pv[nt][r] = p;
        cs += p;
      }
      cs += __shfl_xor(cs, 16);  // sum the wave's 16 rows (across quads)
      cs += __shfl_xor(cs, 32);
      if (lane < 16) atomicAdd(&csum[i0 + nt * 16 + l15], cs);
    }
#pragma unroll
    for (int nt = 0; nt < 4; ++nt)
#pragma unroll
      for (int r = 0; r < 4; ++r)
        Plds[(wave * 16 + quad * 4 + r) * PROW + nt * 16 + l15] = f32_bf16(pv[nt][r]);
    __syncthreads();

    // PV: D[m=d][n=q] += sum_i V[d,i] * P[q,i]
#pragma unroll
    for (int kcc = 0; kcc < 2; ++kcc) {
      bf16x8 pf[4];
#pragma unroll
      for (int nt = 0; nt < 4; ++nt)
        pf[nt] = *(const bf16x8*)(&Plds[(nt * 16 + l15) * PROW + kcc * 32 + quad * 8]);
#pragma unroll
      for (int mt = 0; mt < 8; ++mt) {
        bf16x8 vf = *(const bf16x8*)(vb + (size_t)(mt * 16) * NTOK + i0 + kcc * 32);
#pragma unroll
        for (int nt = 0; nt < 4; ++nt)
          o[mt][nt] = __builtin_amdgcn_mfma_f32_16x16x32_bf16(vf, pf[nt], o[mt][nt], 0, 0, 0);
      }
    }
  }

  // epilogue: out is (B, D, N) row-major == reference (B, VD, H, W). coalesced fp32.
  {
    float* ob = out + ((size_t)b * DDIM + wave * 128) * NTOK + q0;
#pragma unroll
    for (int mt = 0; mt < 8; ++mt)
#pragma unroll
      for (int nt = 0; nt < 4; ++nt)
#pragma unroll
        for (int r = 0; r < 4; ++r)
          ob[(size_t)(mt * 16 + quad * 4 + r) * NTOK + nt * 16 + l15] = o[mt][nt][r];
  }
  __syncthreads();
  for (int i = tid; i < NTOK; i += 256)
    atomicAdd(&scores_out[(size_t)b * NTOK + i], csum[i]);
}

// ---------------------------------------------------------------------------
extern "C" void kernel_launch(void* const* d_in, const int* in_sizes, int n_in,
                              void* d_out, int out_size, void* d_ws, size_t ws_size,
                              hipStream_t stream) {
  const float* x  = (const float*)d_in[0];
  const float* Wk = (const float*)d_in[1];  // dict order: x, Wk, Wq, Wv
  const float* Wq = (const float*)d_in[2];
  const float* Wv = (const float*)d_in[3];

  float* out = (float*)d_out;
  float* scores_out = out + (size_t)NB * DDIM * NTOK;  // tail of d_out

  const size_t mat_elems = (size_t)NB * NTOK * DDIM;   // 8388608
  unsigned short* Qt = (unsigned short*)d_ws;
  unsigned short* Kt = Qt + mat_elems;
  unsigned short* Vd = Kt + mat_elems;                 // total 50.3 MB of ws

  // scores_out accumulated via atomics -> zero it (d_out is poisoned each launch)
  hipMemsetAsync(scores_out, 0, (size_t)NB * NTOK * sizeof(float), stream);

  dim3 g1(NTOK / 64, DDIM / 64, NB);
  qkv_proj<<<g1, 256, 0, stream>>>(x, Wq, Wk, Wv, Qt, Kt, Vd);

  dim3 g2(NTOK / BQ, NB);
  attn_fused<<<g2, 256, 0, stream>>>(Qt, Kt, Vd, out, scores_out);
}

// Round 2
// 732.955 us; speedup vs baseline: 1.3205x; 1.3205x over previous
//
#include <hip/hip_runtime.h>

// B=4, C=512, H=W=64 -> N=4096 tokens, KEY_DIM=VALUE_DIM=512.
// Pipeline:
//   K1 qkv_proj : Qt,Kt (B,N,D) bf16 token-major; Vd (B,D,N) bf16 d-major (ws).
//   K2 attn_lsum: l_j = sum_i exp(q_j.k_i/sqrt(D)); key-split 4 ways -> 1024 WGs
//                 (4 WGs/CU) for latency hiding. fp32 atomicAdd into l (ws).
//   K3 attn_out : recompute QK^T, P = exp*(1/l_j), O = V.P^T + colsum; key-split
//                 2 ways -> 512 WGs (2 WGs/CU, reg-capped). O merged via HW fp32
//                 unsafeAtomicAdd (out pre-zeroed by memset).
// No max-subtraction needed in softmax: logits ~ N(0,1).

typedef short bf16x8 __attribute__((ext_vector_type(8)));
typedef float f32x4 __attribute__((ext_vector_type(4)));

#define NTOK 4096
#define DDIM 512
#define NB   4

__device__ __forceinline__ unsigned short f32_bf16(float f) {
  union { float f; unsigned u; } v; v.f = f;
  unsigned r = v.u + 0x7FFFu + ((v.u >> 16) & 1u);  // RNE
  return (unsigned short)(r >> 16);
}

// ---------------------------------------------------------------------------
// K1: QKV projection.  Q[n,d] = sum_c x[c,n] * Wq[d,c]  (x is (C,N) per batch)
// ---------------------------------------------------------------------------
__global__ __launch_bounds__(256, 4) void qkv_proj(
    const float* __restrict__ x,
    const float* __restrict__ Wq,
    const float* __restrict__ Wk,
    const float* __restrict__ Wv,
    unsigned short* __restrict__ Qt,
    unsigned short* __restrict__ Kt,
    unsigned short* __restrict__ Vd)
{
  const int nt0 = blockIdx.x * 64;   // token tile
  const int d0  = blockIdx.y * 64;   // feature tile
  const int b   = blockIdx.z;
  const int tid = threadIdx.x;
  const int wave = tid >> 6;
  const int lane = tid & 63;
  const int l15  = lane & 15;
  const int quad = lane >> 4;

  __shared__ __align__(16) unsigned short Xt[64 * 40];     // [token][c]
  __shared__ __align__(16) unsigned short Wl[3][64 * 40];  // [q/k/v][d][c]

  f32x4 aq[4], ak[4], av[4];
#pragma unroll
  for (int i = 0; i < 4; ++i) {
    aq[i] = (f32x4){0.f,0.f,0.f,0.f};
    ak[i] = (f32x4){0.f,0.f,0.f,0.f};
    av[i] = (f32x4){0.f,0.f,0.f,0.f};
  }

  const float* xb = x + (size_t)b * DDIM * NTOK + nt0;
  const int xn  = tid & 63;
  const int xc8 = tid >> 6;
  const int wc8 = tid & 3;
  const int wdd = tid >> 2;

  for (int cc = 0; cc < DDIM; cc += 32) {
    __syncthreads();
    {
      bf16x8 t;
#pragma unroll
      for (int j = 0; j < 8; ++j)
        t[j] = (short)f32_bf16(xb[(size_t)(cc + xc8 * 8 + j) * NTOK + xn]);
      *(bf16x8*)(&Xt[xn * 40 + xc8 * 8]) = t;
    }
    {
      const float* wsrc[3] = {Wq, Wk, Wv};
#pragma unroll
      for (int m = 0; m < 3; ++m) {
        const float* src = wsrc[m] + (size_t)(d0 + wdd) * DDIM + cc + wc8 * 8;
        bf16x8 t;
#pragma unroll
        for (int j = 0; j < 8; ++j) t[j] = (short)f32_bf16(src[j]);
        *(bf16x8*)(&Wl[m][wdd * 40 + wc8 * 8]) = t;
      }
    }
    __syncthreads();

    bf16x8 xa  = *(const bf16x8*)(&Xt[(wave * 16 + l15) * 40 + quad * 8]);
    bf16x8 wva = *(const bf16x8*)(&Wl[2][(wave * 16 + l15) * 40 + quad * 8]);
#pragma unroll
    for (int nt = 0; nt < 4; ++nt) {
      bf16x8 wqf = *(const bf16x8*)(&Wl[0][(nt * 16 + l15) * 40 + quad * 8]);
      bf16x8 wkf = *(const bf16x8*)(&Wl[1][(nt * 16 + l15) * 40 + quad * 8]);
      bf16x8 xbf = *(const bf16x8*)(&Xt[(nt * 16 + l15) * 40 + quad * 8]);
      aq[nt] = __builtin_amdgcn_mfma_f32_16x16x32_bf16(xa,  wqf, aq[nt], 0, 0, 0);
      ak[nt] = __builtin_amdgcn_mfma_f32_16x16x32_bf16(xa,  wkf, ak[nt], 0, 0, 0);
      av[nt] = __builtin_amdgcn_mfma_f32_16x16x32_bf16(wva, xbf, av[nt], 0, 0, 0);
    }
  }

#pragma unroll
  for (int nt = 0; nt < 4; ++nt) {
#pragma unroll
    for (int r = 0; r < 4; ++r) {
      const int tokq = nt0 + wave * 16 + quad * 4 + r;
      const int dq   = d0 + nt * 16 + l15;
      Qt[((size_t)b * NTOK + tokq) * DDIM + dq] = f32_bf16(aq[nt][r]);
      Kt[((size_t)b * NTOK + tokq) * DDIM + dq] = f32_bf16(ak[nt][r]);
      const int dv   = d0 + wave * 16 + quad * 4 + r;
      const int tokv = nt0 + nt * 16 + l15;
      Vd[((size_t)b * DDIM + dv) * NTOK + tokv] = f32_bf16(av[nt][r]);
    }
  }
}

// ---------------------------------------------------------------------------
// attention common
// ---------------------------------------------------------------------------
#define BK   64
#define DSUB 256
#define KROW 264   // 256 + 8 pad
#define PROW 72    // 64 + 8 pad
#define SCALE 0.044194173824159216f  // 1/sqrt(512)

__device__ __forceinline__ void stage_k(const unsigned short* __restrict__ src,
                                        unsigned short* __restrict__ Klds,
                                        int tid, int dsi) {
#pragma unroll
  for (int it = 0; it < 8; ++it) {
    const int li = tid + it * 256;
    const int ri = li >> 5;
    const int c8 = li & 31;
    *(bf16x8*)(&Klds[ri * KROW + c8 * 8]) =
        *(const bf16x8*)(src + (size_t)ri * DDIM + dsi * DSUB + c8 * 8);
  }
}

// ---------------------------------------------------------------------------
// K2: row sums l_j.  Grid (NTOK/64, 4 kparts, NB) = 1024 WGs -> 4 WGs/CU.
// ---------------------------------------------------------------------------
__global__ __launch_bounds__(256, 4) void attn_lsum(
    const unsigned short* __restrict__ Qt,
    const unsigned short* __restrict__ Kt,
    float* __restrict__ lsum_g)
{
  const int q0 = blockIdx.x * 64;
  const int k0 = blockIdx.y * (NTOK / 4);
  const int b  = blockIdx.z;
  const int tid = threadIdx.x;
  const int wave = tid >> 6;
  const int lane = tid & 63;
  const int l15  = lane & 15;
  const int quad = lane >> 4;

  __shared__ __align__(16) unsigned short Klds[BK * KROW];  // 33792 B

  bf16x8 qf[16];
  {
    const unsigned short* qp =
        Qt + ((size_t)b * NTOK + q0 + wave * 16 + l15) * DDIM + quad * 8;
#pragma unroll
    for (int dc = 0; dc < 16; ++dc) qf[dc] = *(const bf16x8*)(qp + dc * 32);
  }

  const unsigned short* kb = Kt + (size_t)b * NTOK * DDIM;
  float ls[4] = {0.f, 0.f, 0.f, 0.f};

  for (int kc = 0; kc < (NTOK / 4) / BK; ++kc) {
    const unsigned short* ksrc = kb + (size_t)(k0 + kc * BK) * DDIM;
    f32x4 sacc[4];
#pragma unroll
    for (int i = 0; i < 4; ++i) sacc[i] = (f32x4){0.f,0.f,0.f,0.f};
#pragma unroll
    for (int dsi = 0; dsi < 2; ++dsi) {
      __syncthreads();
      stage_k(ksrc, Klds, tid, dsi);
      __syncthreads();
#pragma unroll
      for (int dc = 0; dc < 8; ++dc) {
        const int ko = dc * 32 + quad * 8;
        const bf16x8 a = qf[dsi * 8 + dc];
#pragma unroll
        for (int nt = 0; nt < 4; ++nt) {
          bf16x8 kf = *(const bf16x8*)(&Klds[(nt * 16 + l15) * KROW + ko]);
          sacc[nt] = __builtin_amdgcn_mfma_f32_16x16x32_bf16(a, kf, sacc[nt], 0, 0, 0);
        }
      }
    }
#pragma unroll
    for (int nt = 0; nt < 4; ++nt)
#pragma unroll
      for (int r = 0; r < 4; ++r) ls[r] += __expf(sacc[nt][r] * SCALE);
  }

#pragma unroll
  for (int r = 0; r < 4; ++r) {
    float v = ls[r];
    v += __shfl_xor(v, 1);
    v += __shfl_xor(v, 2);
    v += __shfl_xor(v, 4);
    v += __shfl_xor(v, 8);
    if (l15 == 0)
      unsafeAtomicAdd(&lsum_g[(size_t)b * NTOK + q0 + wave * 16 + quad * 4 + r], v);
  }
}

// ---------------------------------------------------------------------------
// K3: O = V.P^T (+colsum).  Grid (NTOK/64, 2 kparts, NB) = 512 WGs -> 2 WGs/CU
// (reg-capped at 2 anyway: 128-reg O accumulator + 64-reg Q frags).
// ---------------------------------------------------------------------------
__global__ __launch_bounds__(256, 2) void attn_out(
    const unsigned short* __restrict__ Qt,
    const unsigned short* __restrict__ Kt,
    const unsigned short* __restrict__ Vd,
    const float* __restrict__ lsum_g,
    float* __restrict__ out,
    float* __restrict__ scores_out)
{
  const int q0 = blockIdx.x * 64;
  const int k0 = blockIdx.y * (NTOK / 2);
  const int b  = blockIdx.z;
  const int tid = threadIdx.x;
  const int wave = tid >> 6;
  const int lane = tid & 63;
  const int l15  = lane & 15;
  const int quad = lane >> 4;

  __shared__ __align__(16) unsigned short Klds[BK * KROW];  // 33792 B
  __shared__ __align__(16) unsigned short Plds[64 * PROW];  //  9216 B

  bf16x8 qf[16];
  {
    const unsigned short* qp =
        Qt + ((size_t)b * NTOK + q0 + wave * 16 + l15) * DDIM + quad * 8;
#pragma unroll
    for (int dc = 0; dc < 16; ++dc) qf[dc] = *(const bf16x8*)(qp + dc * 32);
  }

  float rl[4];
#pragma unroll
  for (int r = 0; r < 4; ++r)
    rl[r] = 1.0f / lsum_g[(size_t)b * NTOK + q0 + wave * 16 + quad * 4 + r];

  f32x4 o[8][4];
#pragma unroll
  for (int i = 0; i < 8; ++i)
#pragma unroll
    for (int j = 0; j < 4; ++j) o[i][j] = (f32x4){0.f,0.f,0.f,0.f};

  const unsigned short* kb = Kt + (size_t)b * NTOK * DDIM;
  const unsigned short* vb =
      Vd + ((size_t)b * DDIM + wave * 128 + l15) * NTOK + quad * 8;

  for (int kc = 0; kc < (NTOK / 2) / BK; ++kc) {
    const int i0 = k0 + kc * BK;
    const unsigned short* ksrc = kb + (size_t)i0 * DDIM;
    f32x4 sacc[4];
#pragma unroll
    for (int i = 0; i < 4; ++i) sacc[i] = (f32x4){0.f,0.f,0.f,0.f};
#pragma unroll
    for (int dsi = 0; dsi < 2; ++dsi) {
      __syncthreads();  // also protects Plds reads of previous iteration
      stage_k(ksrc, Klds, tid, dsi);
      __syncthreads();
#pragma unroll
      for (int dc = 0; dc < 8; ++dc) {
        const int ko = dc * 32 + quad * 8;
        const bf16x8 a = qf[dsi * 8 + dc];
#pragma unroll
        for (int nt = 0; nt < 4; ++nt) {
          bf16x8 kf = *(const bf16x8*)(&Klds[(nt * 16 + l15) * KROW + ko]);
          sacc[nt] = __builtin_amdgcn_mfma_f32_16x16x32_bf16(a, kf, sacc[nt], 0, 0, 0);
        }
      }
    }

    // P = exp(s)/l_j ; colsum partials straight to global (pre-zeroed)
    float pv[4][4];
#pragma unroll
    for (int nt = 0; nt < 4; ++nt) {
      float cs = 0.f;
#pragma unroll
      for (int r = 0; r < 4; ++r) {
        const float p = __expf(sacc[nt][r] * SCALE) * rl[r];
        pv[nt][r] = p;
        cs += p;
      }
      cs += __shfl_xor(cs, 16);
      cs += __shfl_xor(cs, 32);
      if (lane < 16)
        unsafeAtomicAdd(&scores_out[(size_t)b * NTOK + i0 + nt * 16 + l15], cs);
    }
#pragma unroll
    for (int nt = 0; nt < 4; ++nt)
#pragma unroll
      for (int r = 0; r < 4; ++r)
        Plds[(wave * 16 + quad * 4 + r) * PROW + nt * 16 + l15] = f32_bf16(pv[nt][r]);
    __syncthreads();

    // PV: D[m=d][n=q] += sum_i V[d,i] * P[q,i]
#pragma unroll
    for (int kcc = 0; kcc < 2; ++kcc) {
      bf16x8 pf[4];
#pragma unroll
      for (int nt = 0; nt < 4; ++nt)
        pf[nt] = *(const bf16x8*)(&Plds[(nt * 16 + l15) * PROW + kcc * 32 + quad * 8]);
#pragma unroll
      for (int mt = 0; mt < 8; ++mt) {
        bf16x8 vf = *(const bf16x8*)(vb + (size_t)(mt * 16) * NTOK + i0 + kcc * 32);
#pragma unroll
        for (int nt = 0; nt < 4; ++nt)
          o[mt][nt] = __builtin_amdgcn_mfma_f32_16x16x32_bf16(vf, pf[nt], o[mt][nt], 0, 0, 0);
      }
    }
  }

  // merge O partials (2 kparts) with HW fp32 atomics; out pre-zeroed
  {
    float* ob = out + ((size_t)b * DDIM + wave * 128) * NTOK + q0;
#pragma unroll
    for (int mt = 0; mt < 8; ++mt)
#pragma unroll
      for (int nt = 0; nt < 4; ++nt)
#pragma unroll
        for (int r = 0; r < 4; ++r)
          unsafeAtomicAdd(&ob[(size_t)(mt * 16 + quad * 4 + r) * NTOK + nt * 16 + l15],
                          o[mt][nt][r]);
  }
}

// ---------------------------------------------------------------------------
extern "C" void kernel_launch(void* const* d_in, const int* in_sizes, int n_in,
                              void* d_out, int out_size, void* d_ws, size_t ws_size,
                              hipStream_t stream) {
  const float* x  = (const float*)d_in[0];
  const float* Wk = (const float*)d_in[1];  // dict order: x, Wk, Wq, Wv
  const float* Wq = (const float*)d_in[2];
  const float* Wv = (const float*)d_in[3];

  float* out = (float*)d_out;
  float* scores_out = out + (size_t)NB * DDIM * NTOK;  // tail of d_out

  const size_t mat_elems = (size_t)NB * NTOK * DDIM;   // 8388608
  unsigned short* Qt = (unsigned short*)d_ws;
  unsigned short* Kt = Qt + mat_elems;
  unsigned short* Vd = Kt + mat_elems;
  float* lbuf = (float*)(Vd + mat_elems);              // 64 KB; ws total ~50.4 MB

  hipMemsetAsync(lbuf, 0, (size_t)NB * NTOK * sizeof(float), stream);
  hipMemsetAsync(scores_out, 0, (size_t)NB * NTOK * sizeof(float), stream);
  hipMemsetAsync(out, 0, (size_t)NB * DDIM * NTOK * sizeof(float), stream);

  dim3 g1(NTOK / 64, DDIM / 64, NB);
  qkv_proj<<<g1, 256, 0, stream>>>(x, Wq, Wk, Wv, Qt, Kt, Vd);

  dim3 g2(NTOK / 64, 4, NB);
  attn_lsum<<<g2, 256, 0, stream>>>(Qt, Kt, lbuf);

  dim3 g3(NTOK / 64, 2, NB);
  attn_out<<<g3, 256, 0, stream>>>(Qt, Kt, Vd, lbuf, out, scores_out);
}

// Round 3
// 644.605 us; speedup vs baseline: 1.5014x; 1.1371x over previous
//
#include <hip/hip_runtime.h>

// B=4, C=512, H=W=64 -> N=4096 tokens, KEY_DIM=VALUE_DIM=512.
// Pipeline (all matmuls on v_mfma_f32_16x16x32_bf16, fp32 accum):
//   K1 qkv_proj  : Qt,Kt (B,N,D) bf16 token-major; Vd (B,D,N) bf16 d-major (ws).
//   K2 attn_lsum_p: S=QK^T/sqrt(D); store Pexp=exp(S) bf16 to ws as [b][q][i]
//                  (exactly the B-operand fragment layout for K3); accumulate
//                  l_j via fp32 atomics. Key-split 4 -> 1024 WGs (4 WGs/CU).
//   K3 attn_pv   : O = V . Pexp^T with BOTH operands read directly from global
//                  (no LDS, no barriers); 1/l folded into epilogue (per-column
//                  scale); colsum computed from the in-flight P fragments.
// No max-subtraction in softmax: logits ~ N(0,1), exp() can't overflow.
// ws budget: QKV 50.3 MB + l 64 KB + Pexp 134.2 MB = 184.7 MB.

typedef short bf16x8 __attribute__((ext_vector_type(8)));
typedef float f32x4 __attribute__((ext_vector_type(4)));

#define NTOK 4096
#define DDIM 512
#define NB   4

__device__ __forceinline__ unsigned short f32_bf16(float f) {
  union { float f; unsigned u; } v; v.f = f;
  unsigned r = v.u + 0x7FFFu + ((v.u >> 16) & 1u);  // RNE
  return (unsigned short)(r >> 16);
}

__device__ __forceinline__ float bf16_f32(short s) {
  union { unsigned u; float f; } v;
  v.u = ((unsigned)(unsigned short)s) << 16;
  return v.f;
}

// ---------------------------------------------------------------------------
// K1: QKV projection.  Q[n,d] = sum_c x[c,n] * Wq[d,c]  (x is (C,N) per batch)
// ---------------------------------------------------------------------------
__global__ __launch_bounds__(256, 4) void qkv_proj(
    const float* __restrict__ x,
    const float* __restrict__ Wq,
    const float* __restrict__ Wk,
    const float* __restrict__ Wv,
    unsigned short* __restrict__ Qt,
    unsigned short* __restrict__ Kt,
    unsigned short* __restrict__ Vd)
{
  const int nt0 = blockIdx.x * 64;   // token tile
  const int d0  = blockIdx.y * 64;   // feature tile
  const int b   = blockIdx.z;
  const int tid = threadIdx.x;
  const int wave = tid >> 6;
  const int lane = tid & 63;
  const int l15  = lane & 15;
  const int quad = lane >> 4;

  __shared__ __align__(16) unsigned short Xt[64 * 40];     // [token][c]
  __shared__ __align__(16) unsigned short Wl[3][64 * 40];  // [q/k/v][d][c]

  f32x4 aq[4], ak[4], av[4];
#pragma unroll
  for (int i = 0; i < 4; ++i) {
    aq[i] = (f32x4){0.f,0.f,0.f,0.f};
    ak[i] = (f32x4){0.f,0.f,0.f,0.f};
    av[i] = (f32x4){0.f,0.f,0.f,0.f};
  }

  const float* xb = x + (size_t)b * DDIM * NTOK + nt0;
  const int xn  = tid & 63;
  const int xc8 = tid >> 6;
  const int wc8 = tid & 3;
  const int wdd = tid >> 2;

  for (int cc = 0; cc < DDIM; cc += 32) {
    __syncthreads();
    {
      bf16x8 t;
#pragma unroll
      for (int j = 0; j < 8; ++j)
        t[j] = (short)f32_bf16(xb[(size_t)(cc + xc8 * 8 + j) * NTOK + xn]);
      *(bf16x8*)(&Xt[xn * 40 + xc8 * 8]) = t;
    }
    {
      const float* wsrc[3] = {Wq, Wk, Wv};
#pragma unroll
      for (int m = 0; m < 3; ++m) {
        const float* src = wsrc[m] + (size_t)(d0 + wdd) * DDIM + cc + wc8 * 8;
        bf16x8 t;
#pragma unroll
        for (int j = 0; j < 8; ++j) t[j] = (short)f32_bf16(src[j]);
        *(bf16x8*)(&Wl[m][wdd * 40 + wc8 * 8]) = t;
      }
    }
    __syncthreads();

    bf16x8 xa  = *(const bf16x8*)(&Xt[(wave * 16 + l15) * 40 + quad * 8]);
    bf16x8 wva = *(const bf16x8*)(&Wl[2][(wave * 16 + l15) * 40 + quad * 8]);
#pragma unroll
    for (int nt = 0; nt < 4; ++nt) {
      bf16x8 wqf = *(const bf16x8*)(&Wl[0][(nt * 16 + l15) * 40 + quad * 8]);
      bf16x8 wkf = *(const bf16x8*)(&Wl[1][(nt * 16 + l15) * 40 + quad * 8]);
      bf16x8 xbf = *(const bf16x8*)(&Xt[(nt * 16 + l15) * 40 + quad * 8]);
      aq[nt] = __builtin_amdgcn_mfma_f32_16x16x32_bf16(xa,  wqf, aq[nt], 0, 0, 0);
      ak[nt] = __builtin_amdgcn_mfma_f32_16x16x32_bf16(xa,  wkf, ak[nt], 0, 0, 0);
      av[nt] = __builtin_amdgcn_mfma_f32_16x16x32_bf16(wva, xbf, av[nt], 0, 0, 0);
    }
  }

#pragma unroll
  for (int nt = 0; nt < 4; ++nt) {
#pragma unroll
    for (int r = 0; r < 4; ++r) {
      const int tokq = nt0 + wave * 16 + quad * 4 + r;
      const int dq   = d0 + nt * 16 + l15;
      Qt[((size_t)b * NTOK + tokq) * DDIM + dq] = f32_bf16(aq[nt][r]);
      Kt[((size_t)b * NTOK + tokq) * DDIM + dq] = f32_bf16(ak[nt][r]);
      const int dv   = d0 + wave * 16 + quad * 4 + r;
      const int tokv = nt0 + nt * 16 + l15;
      Vd[((size_t)b * DDIM + dv) * NTOK + tokv] = f32_bf16(av[nt][r]);
    }
  }
}

// ---------------------------------------------------------------------------
#define BK   64
#define DSUB 256
#define KROW 264   // 256 + 8 pad
#define SCALE 0.044194173824159216f  // 1/sqrt(512)

__device__ __forceinline__ void stage_k(const unsigned short* __restrict__ src,
                                        unsigned short* __restrict__ Klds,
                                        int tid, int dsi) {
#pragma unroll
  for (int it = 0; it < 8; ++it) {
    const int li = tid + it * 256;
    const int ri = li >> 5;
    const int c8 = li & 31;
    *(bf16x8*)(&Klds[ri * KROW + c8 * 8]) =
        *(const bf16x8*)(src + (size_t)ri * DDIM + dsi * DSUB + c8 * 8);
  }
}

// ---------------------------------------------------------------------------
// K2: QK^T -> Pexp store + row-sum atomics. Grid (64, 4 kparts, NB) = 1024 WGs.
// ---------------------------------------------------------------------------
__global__ __launch_bounds__(256, 4) void attn_lsum_p(
    const unsigned short* __restrict__ Qt,
    const unsigned short* __restrict__ Kt,
    unsigned short* __restrict__ Pst,
    float* __restrict__ lsum_g)
{
  const int q0 = blockIdx.x * 64;
  const int k0 = blockIdx.y * (NTOK / 4);
  const int b  = blockIdx.z;
  const int tid = threadIdx.x;
  const int wave = tid >> 6;
  const int lane = tid & 63;
  const int l15  = lane & 15;
  const int quad = lane >> 4;

  __shared__ __align__(16) unsigned short Klds[BK * KROW];  // 33792 B

  bf16x8 qf[16];
  {
    const unsigned short* qp =
        Qt + ((size_t)b * NTOK + q0 + wave * 16 + l15) * DDIM + quad * 8;
#pragma unroll
    for (int dc = 0; dc < 16; ++dc) qf[dc] = *(const bf16x8*)(qp + dc * 32);
  }

  const unsigned short* kb = Kt + (size_t)b * NTOK * DDIM;
  unsigned short* Pb = Pst + (size_t)b * NTOK * NTOK;
  float ls[4] = {0.f, 0.f, 0.f, 0.f};

  for (int kc = 0; kc < (NTOK / 4) / BK; ++kc) {
    const int i0 = k0 + kc * BK;
    const unsigned short* ksrc = kb + (size_t)i0 * DDIM;
    f32x4 sacc[4];
#pragma unroll
    for (int i = 0; i < 4; ++i) sacc[i] = (f32x4){0.f,0.f,0.f,0.f};
#pragma unroll
    for (int dsi = 0; dsi < 2; ++dsi) {
      __syncthreads();
      stage_k(ksrc, Klds, tid, dsi);
      __syncthreads();
#pragma unroll
      for (int dc = 0; dc < 8; ++dc) {
        const int ko = dc * 32 + quad * 8;
        const bf16x8 a = qf[dsi * 8 + dc];
#pragma unroll
        for (int nt = 0; nt < 4; ++nt) {
          bf16x8 kf = *(const bf16x8*)(&Klds[(nt * 16 + l15) * KROW + ko]);
          sacc[nt] = __builtin_amdgcn_mfma_f32_16x16x32_bf16(a, kf, sacc[nt], 0, 0, 0);
        }
      }
    }
    // Pexp = exp(s*scale): store bf16 (C-layout row=q=quad*4+r, col=i=l15)
#pragma unroll
    for (int nt = 0; nt < 4; ++nt) {
#pragma unroll
      for (int r = 0; r < 4; ++r) {
        const float e = __expf(sacc[nt][r] * SCALE);
        ls[r] += e;
        Pb[(size_t)(q0 + wave * 16 + quad * 4 + r) * NTOK + i0 + nt * 16 + l15] =
            f32_bf16(e);
      }
    }
  }

#pragma unroll
  for (int r = 0; r < 4; ++r) {
    float v = ls[r];
    v += __shfl_xor(v, 1);
    v += __shfl_xor(v, 2);
    v += __shfl_xor(v, 4);
    v += __shfl_xor(v, 8);
    if (l15 == 0)
      unsafeAtomicAdd(&lsum_g[(size_t)b * NTOK + q0 + wave * 16 + quad * 4 + r], v);
  }
}

// ---------------------------------------------------------------------------
// K3: O = V . Pexp^T, scaled by 1/l at epilogue; colsum from P fragments.
// No LDS, no barriers: per 32-key chunk = 12 global dwordx4 + 32 MFMA.
// Grid (64, 4 kparts, NB) = 1024 WGs. Wave w owns output d-slice [w*128,w*128+128).
// ---------------------------------------------------------------------------
__global__ __launch_bounds__(256, 2) void attn_pv(
    const unsigned short* __restrict__ Pst,
    const unsigned short* __restrict__ Vd,
    const float* __restrict__ lsum_g,
    float* __restrict__ out,
    float* __restrict__ scores_out)
{
  const int q0 = blockIdx.x * 64;
  const int k0 = blockIdx.y * (NTOK / 4);
  const int b  = blockIdx.z;
  const int tid = threadIdx.x;
  const int wave = tid >> 6;
  const int lane = tid & 63;
  const int l15  = lane & 15;
  const int quad = lane >> 4;

  const unsigned short* Pb = Pst + (size_t)b * NTOK * NTOK;
  const unsigned short* vb =
      Vd + ((size_t)b * DDIM + wave * 128 + l15) * NTOK + quad * 8;

  float rlv[4];
#pragma unroll
  for (int nt = 0; nt < 4; ++nt)
    rlv[nt] = 1.0f / lsum_g[(size_t)b * NTOK + q0 + nt * 16 + l15];

  f32x4 o[8][4];
#pragma unroll
  for (int i = 0; i < 8; ++i)
#pragma unroll
    for (int j = 0; j < 4; ++j) o[i][j] = (f32x4){0.f,0.f,0.f,0.f};

  for (int kc = 0; kc < (NTOK / 4) / 32; ++kc) {
    const int i0 = k0 + kc * 32;

    // P B-fragments: lane = row q (fixed), 8 consecutive i. Direct global.
    bf16x8 pf[4];
#pragma unroll
    for (int nt = 0; nt < 4; ++nt)
      pf[nt] = *(const bf16x8*)(Pb + (size_t)(q0 + nt * 16 + l15) * NTOK + i0 + quad * 8);

    // V A-fragments direct from global, one per 16-d tile.
#pragma unroll
    for (int mt = 0; mt < 8; ++mt) {
      bf16x8 vf = *(const bf16x8*)(vb + (size_t)(mt * 16) * NTOK + i0);
#pragma unroll
      for (int nt = 0; nt < 4; ++nt)
        o[mt][nt] = __builtin_amdgcn_mfma_f32_16x16x32_bf16(vf, pf[nt], o[mt][nt], 0, 0, 0);
    }

    // colsum: scores[i] += sum_q Pexp[q,i] * rl[q].  P already in regs; wave 0 only.
    if (wave == 0) {
      float cj[8];
#pragma unroll
      for (int j = 0; j < 8; ++j) cj[j] = 0.f;
#pragma unroll
      for (int nt = 0; nt < 4; ++nt)
#pragma unroll
        for (int j = 0; j < 8; ++j)
          cj[j] = fmaf(bf16_f32(pf[nt][j]), rlv[nt], cj[j]);
#pragma unroll
      for (int j = 0; j < 8; ++j) {
        float v = cj[j];
        v += __shfl_xor(v, 1);   // reduce over the 16 q-lanes in the quad-group
        v += __shfl_xor(v, 2);
        v += __shfl_xor(v, 4);
        v += __shfl_xor(v, 8);
        if (l15 == 0)
          unsafeAtomicAdd(&scores_out[(size_t)b * NTOK + i0 + quad * 8 + j], v);
      }
    }
  }

  // epilogue: scale by 1/l (per output column q = l15) and merge kparts.
  {
    float* ob = out + ((size_t)b * DDIM + wave * 128) * NTOK + q0;
#pragma unroll
    for (int mt = 0; mt < 8; ++mt)
#pragma unroll
      for (int nt = 0; nt < 4; ++nt)
#pragma unroll
        for (int r = 0; r < 4; ++r)
          unsafeAtomicAdd(&ob[(size_t)(mt * 16 + quad * 4 + r) * NTOK + nt * 16 + l15],
                          o[mt][nt][r] * rlv[nt]);
  }
}

// ---------------------------------------------------------------------------
extern "C" void kernel_launch(void* const* d_in, const int* in_sizes, int n_in,
                              void* d_out, int out_size, void* d_ws, size_t ws_size,
                              hipStream_t stream) {
  const float* x  = (const float*)d_in[0];
  const float* Wk = (const float*)d_in[1];  // dict order: x, Wk, Wq, Wv
  const float* Wq = (const float*)d_in[2];
  const float* Wv = (const float*)d_in[3];

  float* out = (float*)d_out;
  float* scores_out = out + (size_t)NB * DDIM * NTOK;  // tail of d_out

  const size_t mat_elems = (size_t)NB * NTOK * DDIM;   // 8388608
  unsigned short* Qt = (unsigned short*)d_ws;
  unsigned short* Kt = Qt + mat_elems;
  unsigned short* Vd = Kt + mat_elems;
  float* lbuf = (float*)(Vd + mat_elems);              // 64 KB
  unsigned short* Pst = (unsigned short*)(lbuf + (size_t)NB * NTOK);  // 134.2 MB

  hipMemsetAsync(lbuf, 0, (size_t)NB * NTOK * sizeof(float), stream);
  hipMemsetAsync(scores_out, 0, (size_t)NB * NTOK * sizeof(float), stream);
  hipMemsetAsync(out, 0, (size_t)NB * DDIM * NTOK * sizeof(float), stream);

  dim3 g1(NTOK / 64, DDIM / 64, NB);
  qkv_proj<<<g1, 256, 0, stream>>>(x, Wq, Wk, Wv, Qt, Kt, Vd);

  dim3 g2(NTOK / 64, 4, NB);
  attn_lsum_p<<<g2, 256, 0, stream>>>(Qt, Kt, Pst, lbuf);

  dim3 g3(NTOK / 64, 4, NB);
  attn_pv<<<g3, 256, 0, stream>>>(Pst, Vd, lbuf, out, scores_out);
}